// Round 1
// baseline (354.645 us; speedup 1.0000x reference)
//
#include <hip/hip_runtime.h>
#include <hip/hip_bf16.h>
#include <math.h>

// Problem constants (from reference): B=32, C_IN=512, C_HID=512, C_OUT=256, T=4096
#define BB   32
#define CIN  512
#define CHID 512
#define COUT 256
#define TT   4096

// Key insight: reference output = softmax(W2 @ relu(W1 @ x[:,:,-1] + b1) + b2).
// Only the last time step of x is ever consumed -> 32 fused matvec pipelines.
__global__ __launch_bounds__(512) void mlp_last_softmax(
    const float* __restrict__ x,
    const float* __restrict__ W1,
    const float* __restrict__ b1,
    const float* __restrict__ W2,
    const float* __restrict__ b2,
    float* __restrict__ out)
{
    __shared__ float xv[CIN];
    __shared__ float h[CHID];
    __shared__ float ys[COUT];
    __shared__ float redmax[8];
    __shared__ float redsum[8];

    const int b = blockIdx.x;
    const int t = threadIdx.x;

    // Stage x[b, :, T-1] into LDS (strided gather, one element per thread).
    xv[t] = x[(size_t)b * ((size_t)CIN * TT) + (size_t)t * TT + (TT - 1)];
    __syncthreads();

    // h[t] = relu(W1[t, :] . xv + b1[t]) -- one row per thread, float4 loads,
    // 4 independent accumulators for ILP.
    {
        const float4* wr  = reinterpret_cast<const float4*>(W1 + (size_t)t * CIN);
        const float4* xv4 = reinterpret_cast<const float4*>(xv);
        float a0 = 0.f, a1 = 0.f, a2 = 0.f, a3 = 0.f;
        #pragma unroll
        for (int i = 0; i < CIN / 4; i += 4) {
            float4 w0 = wr[i],    w1 = wr[i + 1],  w2 = wr[i + 2],  w3 = wr[i + 3];
            float4 v0 = xv4[i],   v1 = xv4[i + 1], v2 = xv4[i + 2], v3 = xv4[i + 3];
            a0 += w0.x * v0.x + w0.y * v0.y + w0.z * v0.z + w0.w * v0.w;
            a1 += w1.x * v1.x + w1.y * v1.y + w1.z * v1.z + w1.w * v1.w;
            a2 += w2.x * v2.x + w2.y * v2.y + w2.z * v2.z + w2.w * v2.w;
            a3 += w3.x * v3.x + w3.y * v3.y + w3.z * v3.z + w3.w * v3.w;
        }
        float s = (a0 + a1) + (a2 + a3) + b1[t];
        h[t] = fmaxf(s, 0.f);
    }
    __syncthreads();

    // y[o] = W2[o, :] . h + b2[o] -- 2 threads per output row (512 threads /
    // 256 rows), halves combined via shfl_xor(1) (partners share a wave).
    {
        const int o    = t >> 1;
        const int half = t & 1;
        const float4* wr = reinterpret_cast<const float4*>(W2 + (size_t)o * CHID + half * (CHID / 2));
        const float4* h4 = reinterpret_cast<const float4*>(h) + half * (CHID / 8);
        float a0 = 0.f, a1 = 0.f;
        #pragma unroll
        for (int i = 0; i < CHID / 8; i += 2) {
            float4 w0 = wr[i], w1 = wr[i + 1];
            float4 v0 = h4[i], v1 = h4[i + 1];
            a0 += w0.x * v0.x + w0.y * v0.y + w0.z * v0.z + w0.w * v0.w;
            a1 += w1.x * v1.x + w1.y * v1.y + w1.z * v1.z + w1.w * v1.w;
        }
        float acc = a0 + a1;
        acc += __shfl_xor(acc, 1);
        if (half == 0) ys[o] = acc + b2[o];
    }
    __syncthreads();

    // Softmax over ys[0..COUT) -- all 8 waves participate in the reduction,
    // threads >= COUT contribute -inf / 0.
    const int wid  = t >> 6;
    const int lane = t & 63;

    float val = (t < COUT) ? ys[t] : -INFINITY;
    float m = val;
    #pragma unroll
    for (int s = 1; s < 64; s <<= 1) m = fmaxf(m, __shfl_xor(m, s));
    if (lane == 0) redmax[wid] = m;
    __syncthreads();
    float mall = redmax[0];
    #pragma unroll
    for (int i = 1; i < 8; ++i) mall = fmaxf(mall, redmax[i]);

    float e = (t < COUT) ? expf(val - mall) : 0.f;
    float ssum = e;
    #pragma unroll
    for (int s = 1; s < 64; s <<= 1) ssum += __shfl_xor(ssum, s);
    if (lane == 0) redsum[wid] = ssum;
    __syncthreads();
    float tot = 0.f;
    #pragma unroll
    for (int i = 0; i < 8; ++i) tot += redsum[i];

    if (t < COUT) out[(size_t)b * COUT + t] = e / tot;
}

extern "C" void kernel_launch(void* const* d_in, const int* in_sizes, int n_in,
                              void* d_out, int out_size, void* d_ws, size_t ws_size,
                              hipStream_t stream) {
    const float* x  = (const float*)d_in[0];
    const float* W1 = (const float*)d_in[1];
    const float* b1 = (const float*)d_in[2];
    const float* W2 = (const float*)d_in[3];
    const float* b2 = (const float*)d_in[4];
    float* out = (float*)d_out;

    mlp_last_softmax<<<BB, 512, 0, stream>>>(x, W1, b1, W2, b2, out);
}

// Round 2
// 321.899 us; speedup vs baseline: 1.1017x; 1.1017x over previous
//
#include <hip/hip_runtime.h>
#include <hip/hip_bf16.h>
#include <math.h>

// Problem constants (from reference): B=32, C_IN=512, C_HID=512, C_OUT=256, T=4096
#define BB   32
#define CIN  512
#define CHID 512
#define COUT 256
#define TT   4096

// Reference output = softmax(W2 @ relu(W1 @ x[:,:,-1] + b1) + b2).
// Only the last time step of x is consumed -> 32 fused matvec pipelines.
//
// Round 2 structure: split into K1 (hidden matvec, 256 blocks for 8x more
// CU parallelism on the W1 stream) and K2 (output matvec + softmax, 32
// blocks), with h staged in d_ws.

// K1: grid (32, 8), block 256. Block (b, s) computes h[b, s*64 .. s*64+64).
// 4 threads per hidden row, 128 MACs each, quad-combined via shfl_xor.
__global__ __launch_bounds__(256) void k1_hidden(
    const float* __restrict__ x,
    const float* __restrict__ W1,
    const float* __restrict__ b1,
    float* __restrict__ hws)
{
    __shared__ float xv[CIN];

    const int b   = blockIdx.x;
    const int s   = blockIdx.y;
    const int tid = threadIdx.x;

    // Gather x[b, :, T-1] (stride-T, uncoalesced by nature; L2 absorbs the
    // 8x redundancy across splits of the same batch).
    const size_t xbase = (size_t)b * ((size_t)CIN * TT) + (TT - 1);
    xv[tid]       = x[xbase + (size_t)tid * TT];
    xv[tid + 256] = x[xbase + (size_t)(tid + 256) * TT];
    __syncthreads();

    const int rl = tid >> 2;          // local row 0..63
    const int q  = tid & 3;           // quarter 0..3
    const int r  = s * 64 + rl;       // global hidden row

    const float4* wr = reinterpret_cast<const float4*>(W1 + (size_t)r * CIN) + q * 32;
    const float4* xp = reinterpret_cast<const float4*>(xv) + q * 32;

    float a0 = 0.f, a1 = 0.f, a2 = 0.f, a3 = 0.f;
    #pragma unroll
    for (int i = 0; i < 32; i += 4) {
        float4 w0 = wr[i],   w1 = wr[i+1], w2 = wr[i+2], w3 = wr[i+3];
        float4 v0 = xp[i],   v1 = xp[i+1], v2 = xp[i+2], v3 = xp[i+3];
        a0 += w0.x*v0.x + w0.y*v0.y + w0.z*v0.z + w0.w*v0.w;
        a1 += w1.x*v1.x + w1.y*v1.y + w1.z*v1.z + w1.w*v1.w;
        a2 += w2.x*v2.x + w2.y*v2.y + w2.z*v2.z + w2.w*v2.w;
        a3 += w3.x*v3.x + w3.y*v3.y + w3.z*v3.z + w3.w*v3.w;
    }
    float acc = (a0 + a1) + (a2 + a3);
    acc += __shfl_xor(acc, 1);
    acc += __shfl_xor(acc, 2);
    if (q == 0) hws[b * CHID + r] = fmaxf(acc + b1[r], 0.f);
}

// K2: grid 32, block 512. y = W2 @ h + b2, then softmax over 256 outputs.
__global__ __launch_bounds__(512) void k2_out_softmax(
    const float* __restrict__ hws,
    const float* __restrict__ W2,
    const float* __restrict__ b2,
    float* __restrict__ out)
{
    __shared__ float h[CHID];
    __shared__ float ys[COUT];
    __shared__ float redmax[8];
    __shared__ float redsum[8];

    const int b = blockIdx.x;
    const int t = threadIdx.x;

    h[t] = hws[b * CHID + t];   // coalesced, L2-hot
    __syncthreads();

    // 2 threads per output row, halves combined via shfl_xor(1).
    {
        const int o    = t >> 1;
        const int half = t & 1;
        const float4* wr = reinterpret_cast<const float4*>(W2 + (size_t)o * CHID + half * (CHID / 2));
        const float4* h4 = reinterpret_cast<const float4*>(h) + half * (CHID / 8);
        float a0 = 0.f, a1 = 0.f;
        #pragma unroll
        for (int i = 0; i < CHID / 8; i += 2) {
            float4 w0 = wr[i], w1 = wr[i + 1];
            float4 v0 = h4[i], v1 = h4[i + 1];
            a0 += w0.x*v0.x + w0.y*v0.y + w0.z*v0.z + w0.w*v0.w;
            a1 += w1.x*v1.x + w1.y*v1.y + w1.z*v1.z + w1.w*v1.w;
        }
        float acc = a0 + a1;
        acc += __shfl_xor(acc, 1);
        if (half == 0) ys[o] = acc + b2[o];
    }
    __syncthreads();

    // Softmax over ys[0..COUT).
    const int wid  = t >> 6;
    const int lane = t & 63;

    float val = (t < COUT) ? ys[t] : -INFINITY;
    float m = val;
    #pragma unroll
    for (int s = 1; s < 64; s <<= 1) m = fmaxf(m, __shfl_xor(m, s));
    if (lane == 0) redmax[wid] = m;
    __syncthreads();
    float mall = redmax[0];
    #pragma unroll
    for (int i = 1; i < 8; ++i) mall = fmaxf(mall, redmax[i]);

    float e = (t < COUT) ? expf(val - mall) : 0.f;
    float ssum = e;
    #pragma unroll
    for (int s = 1; s < 64; s <<= 1) ssum += __shfl_xor(ssum, s);
    if (lane == 0) redsum[wid] = ssum;
    __syncthreads();
    float tot = 0.f;
    #pragma unroll
    for (int i = 0; i < 8; ++i) tot += redsum[i];

    if (t < COUT) out[(size_t)b * COUT + t] = e / tot;
}

extern "C" void kernel_launch(void* const* d_in, const int* in_sizes, int n_in,
                              void* d_out, int out_size, void* d_ws, size_t ws_size,
                              hipStream_t stream) {
    const float* x  = (const float*)d_in[0];
    const float* W1 = (const float*)d_in[1];
    const float* b1 = (const float*)d_in[2];
    const float* W2 = (const float*)d_in[3];
    const float* b2 = (const float*)d_in[4];
    float* out = (float*)d_out;
    float* hws = (float*)d_ws;   // 32*512 f32 = 64 KB, fully written by K1

    k1_hidden<<<dim3(BB, 8), 256, 0, stream>>>(x, W1, b1, hws);
    k2_out_softmax<<<BB, 512, 0, stream>>>(hws, W2, b2, out);
}